// Round 1
// baseline (204.032 us; speedup 1.0000x reference)
//
#include <hip/hip_runtime.h>
#include <hip/hip_bf16.h>

// Problem constants
#define B_SZ 8
#define L_SEQ 144
#define D_MODEL 256
#define D_INNER 512
#define D_STATE 64
#define DT_RANK 4
#define NTOK (B_SZ * L_SEQ)        // 1152

// ---------------- GEMM: C[M,N] = A[M,K] @ W[N,K]^T  (both K-major) ----------
// BM=BN=64, BK=16, 256 threads, 4x4 microtile. M is always 1152 (divisible).
#define BM 64
#define BN 64
#define BK 16

__global__ __launch_bounds__(256) void gemm_nt(const float* __restrict__ A,
                                               const float* __restrict__ W,
                                               float* __restrict__ C,
                                               int K, int N) {
    __shared__ float As[BK][BM + 4];   // +4 pad: 16B-aligned rows, 2-way max conflict
    __shared__ float Bs[BK][BN + 4];
    const int tid  = threadIdx.x;
    const int m0   = blockIdx.y * BM;
    const int n0   = blockIdx.x * BN;
    const int lrow = tid >> 2;          // 0..63
    const int kq   = (tid & 3) * 4;     // 0,4,8,12
    const int ty   = tid >> 4;          // 0..15
    const int tx   = tid & 15;          // 0..15
    float acc[4][4] = {};

    for (int k0 = 0; k0 < K; k0 += BK) {
        float4 a4 = *(const float4*)(A + (size_t)(m0 + lrow) * K + k0 + kq);
        float4 b4 = make_float4(0.f, 0.f, 0.f, 0.f);
        const int gn = n0 + lrow;
        if (gn < N) b4 = *(const float4*)(W + (size_t)gn * K + k0 + kq);
        __syncthreads();  // previous tile fully consumed before overwrite
        As[kq + 0][lrow] = a4.x; As[kq + 1][lrow] = a4.y;
        As[kq + 2][lrow] = a4.z; As[kq + 3][lrow] = a4.w;
        Bs[kq + 0][lrow] = b4.x; Bs[kq + 1][lrow] = b4.y;
        Bs[kq + 2][lrow] = b4.z; Bs[kq + 3][lrow] = b4.w;
        __syncthreads();
#pragma unroll
        for (int k = 0; k < BK; ++k) {
            float4 av = *(const float4*)&As[k][ty * 4];
            float4 bv = *(const float4*)&Bs[k][tx * 4];
            float a_[4] = {av.x, av.y, av.z, av.w};
            float b_[4] = {bv.x, bv.y, bv.z, bv.w};
#pragma unroll
            for (int i = 0; i < 4; ++i)
#pragma unroll
                for (int j = 0; j < 4; ++j)
                    acc[i][j] = fmaf(a_[i], b_[j], acc[i][j]);
        }
    }
#pragma unroll
    for (int i = 0; i < 4; ++i) {
        const int gm = m0 + ty * 4 + i;
        const int gn = n0 + tx * 4;
        if (gn + 3 < N) {
            *(float4*)(C + (size_t)gm * N + gn) =
                make_float4(acc[i][0], acc[i][1], acc[i][2], acc[i][3]);
        } else {
#pragma unroll
            for (int j = 0; j < 4; ++j)
                if (gn + j < N) C[(size_t)gm * N + gn + j] = acc[i][j];
        }
    }
}

// ---------------- Depthwise conv(4) + SiLU ---------------------------------
// ix[b,t,d] = silu( sum_k w[d,k]*ixpre[b,t+k-2,d] + cb[d] ), ixpre = xz[...,0:512]
__global__ __launch_bounds__(256) void conv_silu_k(const float* __restrict__ xz,
                                                   const float* __restrict__ cw,
                                                   const float* __restrict__ cb,
                                                   float* __restrict__ ix) {
    const int idx = blockIdx.x * 256 + threadIdx.x;   // < NTOK*D_INNER
    const int d = idx & (D_INNER - 1);
    const int token = idx >> 9;
    const int b = token / L_SEQ;
    const int t = token - b * L_SEQ;
    float s = cb[d];
    const float* w = cw + d * 4;
#pragma unroll
    for (int k = 0; k < 4; ++k) {
        const int tt = t + k - 2;
        if (tt >= 0 && tt < L_SEQ)
            s = fmaf(w[k], xz[(size_t)(b * L_SEQ + tt) * 1024 + d], s);
    }
    ix[idx] = s / (1.f + expf(-s));   // silu
}

// ---------------- delta + packed per-(token,d) scalars ---------------------
// aux = {delta, delta*ix, Dp*ix, silu(z)}
__global__ __launch_bounds__(256) void aux_k(const float* __restrict__ dBC,
                                             const float* __restrict__ ix,
                                             const float* __restrict__ xz,
                                             const float* __restrict__ W_dt,
                                             const float* __restrict__ b_dt,
                                             const float* __restrict__ Dp,
                                             float4* __restrict__ aux) {
    const int idx = blockIdx.x * 256 + threadIdx.x;
    const int d = idx & (D_INNER - 1);
    const int token = idx >> 9;
    const float* dt = dBC + (size_t)token * 132;
    const float4 w = *(const float4*)(W_dt + d * 4);
    float s = b_dt[d];
    s = fmaf(dt[0], w.x, s);
    s = fmaf(dt[1], w.y, s);
    s = fmaf(dt[2], w.z, s);
    s = fmaf(dt[3], w.w, s);
    // stable softplus
    const float delta = fmaxf(s, 0.f) + log1pf(expf(-fabsf(s)));
    const float ixv = ix[idx];
    const float zv  = xz[(size_t)token * 1024 + D_INNER + d];
    const float siluz = zv / (1.f + expf(-zv));
    aux[idx] = make_float4(delta, delta * ixv, Dp[d] * ixv, siluz);
}

// ---------------- Selective scan: one wave per (b,d), lane = state n -------
// g[b,t,d] = (sum_n h_t[n]*C[t,n] + Dp*ix) * silu(z)
__global__ __launch_bounds__(64) void scan_k(const float* __restrict__ dBC,
                                             const float4* __restrict__ aux,
                                             const float* __restrict__ A_log,
                                             float* __restrict__ g) {
    __shared__ float P[64][65];   // [t_local][n], +1 pad -> 2-way max conflict
    const int b = blockIdx.x >> 9;
    const int d = blockIdx.x & (D_INNER - 1);
    const int n = threadIdx.x;
    // A[d][n] = -exp(A_log[d][n]); fold log2(e) for exp2f
    const float An2 = -expf(A_log[d * D_STATE + n]) * 1.4426950408889634f;
    float h = 0.f;
    const int base_tok = b * L_SEQ;

    for (int c = 0; c < 3; ++c) {
        const int cnt = (c < 2) ? 64 : (L_SEQ - 128);   // 64,64,16
        const int t0 = c * 64;
        for (int i = 0; i < cnt; ++i) {
            const int token = base_tok + t0 + i;
            const float4 a4 = aux[(size_t)token * D_INNER + d];   // broadcast
            const float Bv = dBC[(size_t)token * 132 + DT_RANK + n];
            const float Cv = dBC[(size_t)token * 132 + DT_RANK + D_STATE + n];
            const float dA = exp2f(a4.x * An2);        // exp(delta*A)
            h = fmaf(dA, h, a4.y * Bv);                // h = dA*h + delta*ix*B
            P[i][n] = h * Cv;
        }
        __syncthreads();
        if (n < cnt) {   // transposed reduce: lane n sums timestep t0+n over all states
            float s2 = 0.f;
#pragma unroll 8
            for (int j = 0; j < 64; ++j) s2 += P[n][j];
            const int token = base_tok + t0 + n;
            const float4 a4 = aux[(size_t)token * D_INNER + d];
            g[(size_t)token * D_INNER + d] = (s2 + a4.z) * a4.w;
        }
        __syncthreads();
    }
}

// ---------------------------------------------------------------------------
extern "C" void kernel_launch(void* const* d_in, const int* in_sizes, int n_in,
                              void* d_out, int out_size, void* d_ws, size_t ws_size,
                              hipStream_t stream) {
    const float* x      = (const float*)d_in[0];
    // d_in[1] = lastin (unused by reference: h0 is fresh zeros)
    const float* W_in   = (const float*)d_in[2];
    const float* conv_w = (const float*)d_in[3];
    const float* conv_b = (const float*)d_in[4];
    const float* W_x    = (const float*)d_in[5];
    const float* W_dt   = (const float*)d_in[6];
    const float* b_dt   = (const float*)d_in[7];
    const float* A_log  = (const float*)d_in[8];
    const float* Dp     = (const float*)d_in[9];
    const float* W_out  = (const float*)d_in[10];
    float* out = (float*)d_out;

    float* ws   = (float*)d_ws;
    float* xz   = ws;                      // NTOK*1024 = 1,179,648 floats
    float* ix   = xz + NTOK * 1024;        // NTOK*512  =   589,824 (later reused as g)
    float* dBC  = ix + NTOK * D_INNER;     // NTOK*132  =   152,064
    float* aux  = dBC + NTOK * 132;        // NTOK*512*4 = 2,359,296 (16B-aligned offset)

    // 1) xz = x @ W_in^T   (1152 x 1024, K=256)
    gemm_nt<<<dim3(1024 / BN, NTOK / BM), 256, 0, stream>>>(x, W_in, xz, D_MODEL, 2 * D_INNER);
    // 2) depthwise conv + silu -> ix
    conv_silu_k<<<dim3(NTOK * D_INNER / 256), 256, 0, stream>>>(xz, conv_w, conv_b, ix);
    // 3) dBC = ix @ W_x^T  (1152 x 132, K=512)
    gemm_nt<<<dim3(3, NTOK / BM), 256, 0, stream>>>(ix, W_x, dBC, D_INNER, 132);
    // 4) delta/softplus + packed scalars
    aux_k<<<dim3(NTOK * D_INNER / 256), 256, 0, stream>>>(dBC, ix, xz, W_dt, b_dt, Dp,
                                                          (float4*)aux);
    // 5) scan -> g (reuse ix buffer)
    scan_k<<<dim3(B_SZ * D_INNER), 64, 0, stream>>>(dBC, (const float4*)aux, A_log, ix);
    // 6) out = g @ W_out^T (1152 x 256, K=512)
    gemm_nt<<<dim3(D_MODEL / BN, NTOK / BM), 256, 0, stream>>>(ix, W_out, out, D_INNER, D_MODEL);
}

// Round 2
// 141.046 us; speedup vs baseline: 1.4466x; 1.4466x over previous
//
#include <hip/hip_runtime.h>
#include <hip/hip_bf16.h>

#define B_SZ 8
#define L_SEQ 144
#define NTOK 1152
#define D_MODEL 256
#define D_INNER 512
#define D_STATE 64
#define DT_RANK 4

#define BM 64
#define BN 64
#define BK 16

// ---------------------------------------------------------------------------
// Templated tiled GEMM: C[M,N] += A·B over k in [z*kslab, z*kslab+kslab)
//  A_MK=true : A stored [m][k] (row stride lda)   | false: A stored [k][m]
//  B_NK=true : B stored [k][n]                    | false: B stored [n][k]
//  GN        : guard n<N on B-loads and C-stores (N not multiple of 64)
// Split-K: blockIdx.z selects k-slab; C advanced by z*sstride (slab output).
// ---------------------------------------------------------------------------
template<bool A_MK, bool B_NK, bool GN>
__global__ __launch_bounds__(256) void gemm_k(const float* __restrict__ A,
                                              const float* __restrict__ Bm,
                                              float* __restrict__ C,
                                              const int M, const int N, const int K,
                                              const int lda, const int ldb, const int ldc,
                                              const int kslab, const size_t sstride) {
    __shared__ float As[BK][BM + 4];
    __shared__ float Bs[BK][BN + 4];
    const int tid = threadIdx.x;
    const int m0 = blockIdx.y * BM;
    const int n0 = blockIdx.x * BN;
    const int kbeg = blockIdx.z * kslab;
    const int kend = kbeg + kslab;
    const int ty = tid >> 4, tx = tid & 15;
    const int lrow = tid >> 2, kq = (tid & 3) * 4;   // transpose-load indices
    const int kk = tid >> 4, cc = (tid & 15) * 4;    // direct-load indices
    float acc[4][4] = {};

    for (int k0 = kbeg; k0 < kend; k0 += BK) {
        float4 av, bv;
        if (A_MK) av = *(const float4*)(A + (size_t)(m0 + lrow) * lda + k0 + kq);
        else      av = *(const float4*)(A + (size_t)(k0 + kk) * lda + m0 + cc);
        if (B_NK) {
            bv = *(const float4*)(Bm + (size_t)(k0 + kk) * ldb + n0 + cc);
        } else {
            bv = make_float4(0.f, 0.f, 0.f, 0.f);
            if (!GN || (n0 + lrow) < N)
                bv = *(const float4*)(Bm + (size_t)(n0 + lrow) * ldb + k0 + kq);
        }
        __syncthreads();
        if (A_MK) {
            As[kq + 0][lrow] = av.x; As[kq + 1][lrow] = av.y;
            As[kq + 2][lrow] = av.z; As[kq + 3][lrow] = av.w;
        } else {
            *(float4*)&As[kk][cc] = av;
        }
        if (B_NK) {
            *(float4*)&Bs[kk][cc] = bv;
        } else {
            Bs[kq + 0][lrow] = bv.x; Bs[kq + 1][lrow] = bv.y;
            Bs[kq + 2][lrow] = bv.z; Bs[kq + 3][lrow] = bv.w;
        }
        __syncthreads();
#pragma unroll
        for (int k = 0; k < BK; ++k) {
            const float4 a4 = *(const float4*)&As[k][ty * 4];
            const float4 b4 = *(const float4*)&Bs[k][tx * 4];
            const float a_[4] = {a4.x, a4.y, a4.z, a4.w};
            const float b_[4] = {b4.x, b4.y, b4.z, b4.w};
#pragma unroll
            for (int i = 0; i < 4; ++i)
#pragma unroll
                for (int j = 0; j < 4; ++j)
                    acc[i][j] = fmaf(a_[i], b_[j], acc[i][j]);
        }
    }
    C += (size_t)blockIdx.z * sstride;
#pragma unroll
    for (int i = 0; i < 4; ++i) {
        const int gm = m0 + ty * 4 + i;
        const int gn = n0 + tx * 4;
        if (!GN || gn < N)
            *(float4*)(C + (size_t)gm * ldc + gn) =
                make_float4(acc[i][0], acc[i][1], acc[i][2], acc[i][3]);
    }
}

// ---------------------------------------------------------------------------
// Split-K slab reduction: out[i] = sum_{s<4} in[i + s*s4], float4-wide
// ---------------------------------------------------------------------------
__global__ __launch_bounds__(256) void reduce4_k(const float4* __restrict__ in,
                                                 float4* __restrict__ out,
                                                 const int n4, const int s4) {
    const int i = blockIdx.x * 256 + threadIdx.x;
    if (i >= n4) return;
    const float4 a = in[i], b = in[i + s4], c = in[i + 2 * s4], d = in[i + 3 * s4];
    out[i] = make_float4(a.x + b.x + c.x + d.x, a.y + b.y + c.y + d.y,
                         a.z + b.z + c.z + d.z, a.w + b.w + c.w + d.w);
}

// ---------------------------------------------------------------------------
// Depthwise conv(4) + SiLU on t-major layout: fully coalesced
// ---------------------------------------------------------------------------
__global__ __launch_bounds__(128) void conv_k(const float* __restrict__ xzT,
                                              const float* __restrict__ cw,
                                              const float* __restrict__ cb,
                                              float* __restrict__ ixT) {
    const int tok = blockIdx.x * 128 + threadIdx.x;   // 9*128 = 1152 exact
    const int d = blockIdx.y;
    const int b = tok / L_SEQ;
    const int t = tok - b * L_SEQ;
    const float* row = xzT + (size_t)d * NTOK + tok;
    const float4 w = *(const float4*)(cw + d * 4);
    float s = cb[d];
    if (t >= 2) s = fmaf(w.x, row[-2], s);
    if (t >= 1) s = fmaf(w.y, row[-1], s);
    s = fmaf(w.z, row[0], s);
    if (t < L_SEQ - 1) s = fmaf(w.w, row[1], s);
    ixT[(size_t)d * NTOK + tok] = s * __builtin_amdgcn_rcpf(1.f + __expf(-s));
}

// ---------------------------------------------------------------------------
// Fused aux+scan. One wave per (b,d); lane = state n. Per 32-token chunk:
//   pre-pass (lane-parallel): delta=softplus(dt·Wdt+b), delta*ix, Dp*ix, silu(z)
//   serial : h = exp2(delta*An2)*h + (delta*ix)*B[t][n];  P[t][n] = h*C[t][n]
//   reduce : transposed LDS row-sum (half-row per lane + shfl_xor 32)
// No __syncthreads: each wave owns its own aux/P LDS slice.
// ---------------------------------------------------------------------------
template<int CNT>
__device__ __forceinline__ void scan_chunk(const float* __restrict__ dBC,
                                           const float* __restrict__ xzT,
                                           const float* __restrict__ ixT,
                                           float* __restrict__ gT,
                                           float4* __restrict__ aux_w,
                                           float (*__restrict__ Pw)[65],
                                           const int d, const int base, const int t0,
                                           const float An2, const float4 wdt,
                                           const float bdt, const float dpv,
                                           const int lane, float& h) {
    if (lane < CNT) {
        const int tok = base + t0 + lane;
        const float4 dt4 = *(const float4*)(dBC + (size_t)tok * 132);
        float s = fmaf(dt4.x, wdt.x, bdt);
        s = fmaf(dt4.y, wdt.y, s);
        s = fmaf(dt4.z, wdt.z, s);
        s = fmaf(dt4.w, wdt.w, s);
        const float delta = fmaxf(s, 0.f) + __logf(1.f + __expf(-fabsf(s)));
        const float ixv = ixT[(size_t)d * NTOK + tok];
        const float zv  = xzT[(size_t)(D_INNER + d) * NTOK + tok];
        const float sz  = zv * __builtin_amdgcn_rcpf(1.f + __expf(-zv));
        aux_w[lane] = make_float4(delta, delta * ixv, dpv * ixv, sz);
    }
#pragma unroll 8
    for (int i = 0; i < CNT; ++i) {
        const size_t rb = (size_t)(base + t0 + i) * 132;
        const float Bv = dBC[rb + DT_RANK + lane];                 // coalesced, L2-hot
        const float Cv = dBC[rb + DT_RANK + D_STATE + lane];
        const float4 a4 = aux_w[i];                                // LDS broadcast
        const float dA = __builtin_amdgcn_exp2f(a4.x * An2);       // exp(delta*A)
        h = fmaf(dA, h, a4.y * Bv);
        Pw[i][lane] = h * Cv;
    }
    const int tl = lane & 31, hf = lane >> 5;
    float s2 = 0.f;
    if (tl < CNT) {
#pragma unroll
        for (int j = 0; j < 32; ++j) s2 += Pw[tl][hf * 32 + j];    // 2-way banks: free
    }
    s2 += __shfl_xor(s2, 32, 64);
    if (hf == 0 && tl < CNT) {
        const float4 a4 = aux_w[tl];
        gT[(size_t)d * NTOK + base + t0 + tl] = (s2 + a4.z) * a4.w;  // coalesced
    }
}

__global__ __launch_bounds__(256) void scan_k(const float* __restrict__ dBC,
                                              const float* __restrict__ xzT,
                                              const float* __restrict__ ixT,
                                              const float* __restrict__ W_dt,
                                              const float* __restrict__ b_dt,
                                              const float* __restrict__ A_log,
                                              const float* __restrict__ Dp,
                                              float* __restrict__ gT) {
    __shared__ float4 aux_s[4][32];
    __shared__ float P[4][32][65];
    const int w = threadIdx.x >> 6, lane = threadIdx.x & 63;
    const int b = blockIdx.x >> 7, dg = blockIdx.x & 127;
    const int d = (dg << 2) | w;
    const int base = b * L_SEQ;
    const float An2 = -__expf(A_log[(d << 6) + lane]) * 1.44269504088896f;
    const float4 wdt = *(const float4*)(W_dt + (d << 2));
    const float bdt = b_dt[d], dpv = Dp[d];
    float h = 0.f;
    scan_chunk<32>(dBC, xzT, ixT, gT, aux_s[w], P[w], d, base, 0,  An2, wdt, bdt, dpv, lane, h);
    scan_chunk<32>(dBC, xzT, ixT, gT, aux_s[w], P[w], d, base, 32, An2, wdt, bdt, dpv, lane, h);
    scan_chunk<32>(dBC, xzT, ixT, gT, aux_s[w], P[w], d, base, 64, An2, wdt, bdt, dpv, lane, h);
    scan_chunk<32>(dBC, xzT, ixT, gT, aux_s[w], P[w], d, base, 96, An2, wdt, bdt, dpv, lane, h);
    scan_chunk<16>(dBC, xzT, ixT, gT, aux_s[w], P[w], d, base, 128, An2, wdt, bdt, dpv, lane, h);
}

// ---------------------------------------------------------------------------
extern "C" void kernel_launch(void* const* d_in, const int* in_sizes, int n_in,
                              void* d_out, int out_size, void* d_ws, size_t ws_size,
                              hipStream_t stream) {
    const float* x      = (const float*)d_in[0];
    // d_in[1] = lastin (unused: reference starts from h0 = 0)
    const float* W_in   = (const float*)d_in[2];
    const float* conv_w = (const float*)d_in[3];
    const float* conv_b = (const float*)d_in[4];
    const float* W_x    = (const float*)d_in[5];
    const float* W_dt   = (const float*)d_in[6];
    const float* b_dt   = (const float*)d_in[7];
    const float* A_log  = (const float*)d_in[8];
    const float* Dp     = (const float*)d_in[9];
    const float* W_out  = (const float*)d_in[10];
    float* out = (float*)d_out;

    float* ws    = (float*)d_ws;
    float* xzT   = ws;                  // [1024][1152] = 1,179,648 f
    float* ixT   = xzT + 1179648;       // [512][1152]  =   589,824 f
    float* dBC   = ixT + 589824;        // [1152][132]  =   152,064 f
    float* gT    = dBC + 152064;        // [512][1152]  =   589,824 f
    float* slab3 = gT + 589824;         // 4×152,064    =   608,256 f
    float* slab6 = xzT;                 // reuse: xzT dead after scan (4×294,912 fits)

    // 1) xzT[e][tok] = W_in[e][:] · x[tok][:]   (M=1024, N=1152, K=256)
    gemm_k<true, false, false><<<dim3(18, 16, 1), 256, 0, stream>>>(
        W_in, x, xzT, 1024, NTOK, D_MODEL, D_MODEL, D_MODEL, NTOK, D_MODEL, 0);
    // 2) depthwise conv + silu -> ixT[d][tok]
    conv_k<<<dim3(9, D_INNER), 128, 0, stream>>>(xzT, conv_w, conv_b, ixT);
    // 3) dBC[tok][e] = ix[tok][:] · W_x[e][:]   split-K=4 into slabs
    gemm_k<false, false, true><<<dim3(3, 18, 4), 256, 0, stream>>>(
        ixT, W_x, slab3, NTOK, 132, D_INNER, NTOK, D_INNER, 132, 128, (size_t)NTOK * 132);
    reduce4_k<<<dim3(149), 256, 0, stream>>>((const float4*)slab3, (float4*)dBC,
                                             NTOK * 132 / 4, NTOK * 132 / 4);
    // 4) fused aux + selective scan -> gT[d][tok]
    scan_k<<<dim3(B_SZ * 128), 256, 0, stream>>>(dBC, xzT, ixT, W_dt, b_dt, A_log, Dp, gT);
    // 5) out[tok][e] = g[tok][:] · W_out[e][:]  split-K=4 into slabs (reuse xzT)
    gemm_k<false, false, false><<<dim3(4, 18, 4), 256, 0, stream>>>(
        gT, W_out, slab6, NTOK, D_MODEL, D_INNER, NTOK, D_INNER, D_MODEL, 128,
        (size_t)NTOK * D_MODEL);
    reduce4_k<<<dim3(288), 256, 0, stream>>>((const float4*)slab6, (float4*)out,
                                             NTOK * D_MODEL / 4, NTOK * D_MODEL / 4);
}